// Round 6
// baseline (426.189 us; speedup 1.0000x reference)
//
#include <hip/hip_runtime.h>

#define L_SEQ 2048
#define BATCH 16
#define DDIM  1024
#define MDIM  (L_SEQ * BATCH)   // 32768
#define NDIM  (3 * DDIM)        // 3072
#define KDIM  DDIM              // 1024
#define CH    (BATCH * DDIM)    // 16384
#define NSEG  32
#define SEGL  64                // L_SEQ / NSEG

typedef __attribute__((ext_vector_type(8))) short short8;
typedef __attribute__((ext_vector_type(4))) float f32x4;

static __device__ __forceinline__ unsigned short f2bf(float f) {
  unsigned int u = __builtin_bit_cast(unsigned int, f);
  unsigned int lsb = (u >> 16) & 1u;
  u += 0x7fffu + lsb;
  return (unsigned short)(u >> 16);
}
static __device__ __forceinline__ float bf2f(unsigned short s) {
  unsigned int u = ((unsigned int)s) << 16;
  return __builtin_bit_cast(float, u);
}

static __device__ __forceinline__ void gll16(const void* g, void* l) {
  __builtin_amdgcn_global_load_lds(
      (const __attribute__((address_space(1))) unsigned int*)g,
      (__attribute__((address_space(3))) unsigned int*)l, 16, 0, 0);
}

// ---- converters ----------------------------------------------------------

__global__ void k_convert_x(const float4* __restrict__ x, ushort4* __restrict__ xb, int n4) {
  int i = blockIdx.x * blockDim.x + threadIdx.x;
  int stride = gridDim.x * blockDim.x;
  for (; i < n4; i += stride) {
    float4 v = x[i];
    ushort4 o;
    o.x = f2bf(v.x); o.y = f2bf(v.y); o.z = f2bf(v.z); o.w = f2bf(v.w);
    xb[i] = o;
  }
}

// Wb[n][k] = bf16( W[k][colmap(n)] ): regions {xt, f, r} -> contiguous col ranges
__global__ void k_convert_w(const float* __restrict__ w, unsigned short* __restrict__ wb) {
  int gid = blockIdx.x * 256 + threadIdx.x;   // 3072*1024 total
  int k = gid & (KDIM - 1);
  int n = gid >> 10;
  int col = (n < DDIM) ? 3 * n : (n < 2 * DDIM) ? 3 * (n - DDIM) + 1 : 3 * (n - 2 * DDIM) + 2;
  wb[gid] = f2bf(w[(size_t)k * NDIM + col]);
}

// ---- GEMM: 256x256, BK=64, 8 waves, 1 barrier + 1 vmcnt(0) per K-tile ----
// LDS: 2 buffers x 64KB; buffer = { A_kb0 16K | A_kb1 16K | B_kb0 16K | B_kb1 16K }
// each 16K subtile: 256 rows x 64B, 16B-slot permutation slot^((row>>1)&3) (0 conflicts, proven)
// Schedule (R5 post-mortem): phase barriers removed — reads (bufC) and stages
// (bufN) are disjoint, so the only sync needed per tile is {vmcnt(0); s_barrier}
// at the end. The compute region is fence-free: compiler interleaves ds_read
// latency under MFMAs; source order software-pipelines reads ahead one group.

#define MFMA1(I, J, A, B) \
  acc[I][J] = __builtin_amdgcn_mfma_f32_16x16x32_bf16(A, B, acc[I][J], 0, 0, 0);

#define MFMAQ(BASE, A0, A1, A2, A3, B0, B1, B2, B3)      \
  MFMA1(BASE + 0, 0, A0, B0) MFMA1(BASE + 0, 1, A0, B1)  \
  MFMA1(BASE + 0, 2, A0, B2) MFMA1(BASE + 0, 3, A0, B3)  \
  MFMA1(BASE + 1, 0, A1, B0) MFMA1(BASE + 1, 1, A1, B1)  \
  MFMA1(BASE + 1, 2, A1, B2) MFMA1(BASE + 1, 3, A1, B3)  \
  MFMA1(BASE + 2, 0, A2, B0) MFMA1(BASE + 2, 1, A2, B1)  \
  MFMA1(BASE + 2, 2, A2, B2) MFMA1(BASE + 2, 3, A2, B3)  \
  MFMA1(BASE + 3, 0, A3, B0) MFMA1(BASE + 3, 1, A3, B1)  \
  MFMA1(BASE + 3, 2, A3, B2) MFMA1(BASE + 3, 3, A3, B3)

// One BK=64 tile. T = tile index; stages tile T+1 into the other buffer.
#define TILE64(T) do {                                                        \
  const char* bufC = LDSc + ((T) & 1) * 65536;                                \
  char*       bufN = LDSc + (((T) + 1) & 1) * 65536;                          \
  const int stA = (((T) + 1) & 15) * 128;                                     \
  /* stage ALL of tile T+1 up front (8 gll16), pinned before compute */       \
  gll16(srcA0 + stA, bufN + dstOff);                                          \
  gll16(srcA1 + stA, bufN + 8192 + dstOff);                                   \
  gll16(srcB0 + stA, bufN + 32768 + dstOff);                                  \
  gll16(srcB1 + stA, bufN + 40960 + dstOff);                                  \
  gll16(srcA0 + stA + 64, bufN + 16384 + dstOff);                             \
  gll16(srcA1 + stA + 64, bufN + 24576 + dstOff);                             \
  gll16(srcB0 + stA + 64, bufN + 49152 + dstOff);                             \
  gll16(srcB1 + stA + 64, bufN + 57344 + dstOff);                             \
  __builtin_amdgcn_sched_barrier(0);                                          \
  /* fence-free compute: reads pipelined one group ahead of their MFMAs */    \
  a0 = *(const short8*)(bufC + aRd);                                          \
  a1 = *(const short8*)(bufC + aRd + 1024);                                   \
  a2 = *(const short8*)(bufC + aRd + 2048);                                   \
  a3 = *(const short8*)(bufC + aRd + 3072);                                   \
  b0 = *(const short8*)(bufC + 32768 + bRd);                                  \
  b1 = *(const short8*)(bufC + 32768 + bRd + 1024);                           \
  b2 = *(const short8*)(bufC + 32768 + bRd + 2048);                           \
  b3 = *(const short8*)(bufC + 32768 + bRd + 3072);                           \
  na0 = *(const short8*)(bufC + aRd + 4096);                                  \
  na1 = *(const short8*)(bufC + aRd + 5120);                                  \
  na2 = *(const short8*)(bufC + aRd + 6144);                                  \
  na3 = *(const short8*)(bufC + aRd + 7168);                                  \
  __builtin_amdgcn_s_setprio(1);                                              \
  MFMAQ(0, a0, a1, a2, a3, b0, b1, b2, b3)                                    \
  __builtin_amdgcn_s_setprio(0);                                              \
  a0 = *(const short8*)(bufC + 16384 + aRd);                                  \
  a1 = *(const short8*)(bufC + 16384 + aRd + 1024);                           \
  a2 = *(const short8*)(bufC + 16384 + aRd + 2048);                           \
  a3 = *(const short8*)(bufC + 16384 + aRd + 3072);                           \
  nb0 = *(const short8*)(bufC + 49152 + bRd);                                 \
  nb1 = *(const short8*)(bufC + 49152 + bRd + 1024);                          \
  nb2 = *(const short8*)(bufC + 49152 + bRd + 2048);                          \
  nb3 = *(const short8*)(bufC + 49152 + bRd + 3072);                          \
  __builtin_amdgcn_s_setprio(1);                                              \
  MFMAQ(4, na0, na1, na2, na3, b0, b1, b2, b3)                                \
  __builtin_amdgcn_s_setprio(0);                                              \
  na0 = *(const short8*)(bufC + 16384 + aRd + 4096);                          \
  na1 = *(const short8*)(bufC + 16384 + aRd + 5120);                          \
  na2 = *(const short8*)(bufC + 16384 + aRd + 6144);                          \
  na3 = *(const short8*)(bufC + 16384 + aRd + 7168);                          \
  __builtin_amdgcn_s_setprio(1);                                              \
  MFMAQ(0, a0, a1, a2, a3, nb0, nb1, nb2, nb3)                                \
  MFMAQ(4, na0, na1, na2, na3, nb0, nb1, nb2, nb3)                            \
  __builtin_amdgcn_s_setprio(0);                                              \
  /* single sync point per tile: stages landed + all reads consumed */        \
  asm volatile("s_waitcnt vmcnt(0)" ::: "memory");                            \
  __builtin_amdgcn_s_barrier();                                               \
} while (0)

__global__ __launch_bounds__(512, 2) void k_gemm256(
    const unsigned short* __restrict__ xb,   // [M][K] bf16
    const unsigned short* __restrict__ wb,   // [N][K] bf16
    const float* __restrict__ bias,          // [2d]
    unsigned short* __restrict__ xtb,        // [M][d] bf16
    unsigned short* __restrict__ fbuf,       // [M][d] bf16
    unsigned short* __restrict__ rbuf) {     // [M][d] bf16
  __shared__ char LDS[131072];
  char* LDSc = LDS;

  const int tid  = threadIdx.x;
  const int lane = tid & 63;
  const int wid  = tid >> 6;
  const int wr   = wid >> 2;     // 0..1
  const int wc   = wid & 3;      // 0..3

  // XCD-aware bijective swizzle: 1536 = 8 * 192
  int bid = blockIdx.x;
  int wg = (bid & 7) * 192 + (bid >> 3);
  int mt = wg / 12;
  int nt = wg - mt * 12;
  const int rowBase = mt * 256;
  const int colBase = nt * 256;

  // ds_read bases (16B-slot permutation: phys = slot ^ ((row>>1)&3))
  const int l15 = lane & 15;
  const int sl  = lane >> 4;
  const int ra0 = wr * 128 + l15;
  const int rb0 = wc * 64 + l15;
  const int aRd = ra0 * 64 + (sl ^ ((ra0 >> 1) & 3)) * 16;
  const int bRd = rb0 * 64 + (sl ^ ((rb0 >> 1) & 3)) * 16;

  // staging source bases (inverse permutation on global source, linear LDS dest)
  const int p0i = tid, p1i = 512 + tid;
  const int r0 = p0i >> 2, r1 = p1i >> 2;
  const int s0 = (p0i & 3) ^ ((r0 >> 1) & 3);
  const int s1 = (p1i & 3) ^ ((r1 >> 1) & 3);
  const char* srcA0 = (const char*)xb + (size_t)(rowBase + r0) * 2048 + s0 * 16;
  const char* srcA1 = (const char*)xb + (size_t)(rowBase + r1) * 2048 + s1 * 16;
  const char* srcB0 = (const char*)wb + (size_t)(colBase + r0) * 2048 + s0 * 16;
  const char* srcB1 = (const char*)wb + (size_t)(colBase + r1) * 2048 + s1 * 16;
  const int dstOff = wid * 1024;

  f32x4 acc[8][4];
#pragma unroll
  for (int ii = 0; ii < 8; ++ii)
#pragma unroll
    for (int jj = 0; jj < 4; ++jj)
      acc[ii][jj] = (f32x4){0.f, 0.f, 0.f, 0.f};

  // prologue: stage tile 0 (both K-halves of A and B) into buffer 0
  gll16(srcA0, LDSc + dstOff);
  gll16(srcA1, LDSc + 8192 + dstOff);
  gll16(srcB0, LDSc + 32768 + dstOff);
  gll16(srcB1, LDSc + 40960 + dstOff);
  gll16(srcA0 + 64, LDSc + 16384 + dstOff);
  gll16(srcA1 + 64, LDSc + 24576 + dstOff);
  gll16(srcB0 + 64, LDSc + 49152 + dstOff);
  gll16(srcB1 + 64, LDSc + 57344 + dstOff);
  asm volatile("s_waitcnt vmcnt(0)" ::: "memory");
  __builtin_amdgcn_s_barrier();

  short8 a0, a1, a2, a3, na0, na1, na2, na3;
  short8 b0, b1, b2, b3, nb0, nb1, nb2, nb3;

  for (int i = 0; i < 8; ++i) {
    TILE64(2 * i);
    TILE64(2 * i + 1);
  }

  // epilogue: region 0 -> x_tilde (bf16), 1 -> forget, 2 -> reset
  const int region = colBase >> 10;
#pragma unroll
  for (int qm = 0; qm < 2; ++qm) {
#pragma unroll
    for (int m = 0; m < 4; ++m) {
      int grow = rowBase + wr * 128 + qm * 64 + m * 16 + ((lane >> 4) << 2);
#pragma unroll
      for (int n = 0; n < 4; ++n) {
        int gcol = colBase + wc * 64 + n * 16 + (lane & 15);
        f32x4 v = acc[qm * 4 + m][n];
        if (region == 0) {
#pragma unroll
          for (int j = 0; j < 4; ++j)
            xtb[(size_t)(grow + j) * DDIM + gcol] = f2bf(v[j]);
        } else {
          float bv = bias[gcol - DDIM];
          unsigned short* dst = (region == 1) ? fbuf : rbuf;
          int lcol = gcol - (region << 10);
#pragma unroll
          for (int j = 0; j < 4; ++j) {
            float sg = 1.0f / (1.0f + __expf(-(v[j] + bv)));
            dst[(size_t)(grow + j) * DDIM + lcol] = f2bf(sg);
          }
        }
      }
    }
  }
}

// ---- segmented scan ------------------------------------------------------
// pass 1: per (segment, channel-pair) affine state a = prod f, b = scan from 0

__global__ __launch_bounds__(256) void k_scan1(
    const unsigned short* __restrict__ fbuf,
    const unsigned short* __restrict__ xtb,
    float4* __restrict__ AB) {
  int chp = blockIdx.x * 256 + threadIdx.x;       // 0..8191 channel pairs
  int seg = blockIdx.y;
  size_t base = (size_t)seg * SEGL * CH + chp * 2;
  const unsigned int* fp = (const unsigned int*)(fbuf + base);
  const unsigned int* xp = (const unsigned int*)(xtb + base);
  float a0 = 1.f, a1 = 1.f, b0 = 0.f, b1 = 0.f;
#pragma unroll 8
  for (int s = 0; s < SEGL; ++s) {
    unsigned int fv = fp[(size_t)s * (CH / 2)];
    unsigned int xv = xp[(size_t)s * (CH / 2)];
    float f0 = bf2f((unsigned short)fv), f1 = bf2f((unsigned short)(fv >> 16));
    float x0 = bf2f((unsigned short)xv), x1 = bf2f((unsigned short)(xv >> 16));
    b0 = (b0 - x0) * f0 + x0;  a0 *= f0;
    b1 = (b1 - x1) * f1 + x1;  a1 *= f1;
  }
  AB[(size_t)seg * (CH / 2) + chp] = (float4){a0, b0, a1, b1};
}

// pass 2: scan 32 segment states per channel; emit per-segment c_in and c_last

__global__ __launch_bounds__(256) void k_scan2(
    const float* __restrict__ c0,
    const float4* __restrict__ AB,
    float* __restrict__ Cin,
    float* __restrict__ clast) {
  int chp = blockIdx.x * 256 + threadIdx.x;       // 0..8191
  float2 cc = ((const float2*)c0)[chp];
  float ca = cc.x, cb = cc.y;
#pragma unroll
  for (int s = 0; s < NSEG; ++s) {
    ((float2*)Cin)[(size_t)s * (CH / 2) + chp] = (float2){ca, cb};
    float4 ab = AB[(size_t)s * (CH / 2) + chp];
    ca = ca * ab.x + ab.y;
    cb = cb * ab.z + ab.w;
  }
  ((float2*)clast)[chp] = (float2){ca, cb};
}

// pass 3: recompute c within segment from c_in; emit h

__global__ __launch_bounds__(256) void k_scan3(
    const float* __restrict__ x,
    const unsigned short* __restrict__ fbuf,
    const unsigned short* __restrict__ xtb,
    const unsigned short* __restrict__ rbuf,
    const float* __restrict__ Cin,
    float* __restrict__ h) {
  int chp = blockIdx.x * 256 + threadIdx.x;
  int seg = blockIdx.y;
  float2 cc = ((const float2*)Cin)[(size_t)seg * (CH / 2) + chp];
  float ca = cc.x, cb = cc.y;
  size_t base = (size_t)seg * SEGL * CH + chp * 2;
  const unsigned int* fp = (const unsigned int*)(fbuf + base);
  const unsigned int* tp = (const unsigned int*)(xtb + base);
  const unsigned int* rp = (const unsigned int*)(rbuf + base);
  const float2* xp = (const float2*)(x + base);
  float2* hp = (float2*)(h + base);
#pragma unroll 4
  for (int s = 0; s < SEGL; ++s) {
    unsigned int fv = fp[(size_t)s * (CH / 2)];
    unsigned int tv = tp[(size_t)s * (CH / 2)];
    unsigned int rv = rp[(size_t)s * (CH / 2)];
    float2 xv = xp[(size_t)s * (CH / 2)];
    float f0 = bf2f((unsigned short)fv), f1 = bf2f((unsigned short)(fv >> 16));
    float t0 = bf2f((unsigned short)tv), t1 = bf2f((unsigned short)(tv >> 16));
    float r0 = bf2f((unsigned short)rv), r1 = bf2f((unsigned short)(rv >> 16));
    ca = (ca - t0) * f0 + t0;
    cb = (cb - t1) * f1 + t1;
    float e0 = __expf(-2.f * fabsf(ca));
    float e1 = __expf(-2.f * fabsf(cb));
    float g0 = copysignf((1.f - e0) / (1.f + e0), ca);
    float g1 = copysignf((1.f - e1) / (1.f + e1), cb);
    float h0 = (g0 - xv.x) * r0 + xv.x;
    float h1 = (g1 - xv.y) * r1 + xv.y;
    hp[(size_t)s * (CH / 2)] = (float2){h0, h1};
  }
}

// ---- launch --------------------------------------------------------------

extern "C" void kernel_launch(void* const* d_in, const int* in_sizes, int n_in,
                              void* d_out, int out_size, void* d_ws, size_t ws_size,
                              hipStream_t stream) {
  const float* x    = (const float*)d_in[0];
  const float* w    = (const float*)d_in[1];
  const float* bias = (const float*)d_in[2];
  const float* c0   = (const float*)d_in[3];
  float* out = (float*)d_out;
  char* ws = (char*)d_ws;

  // ws layout (207.6 MB total):
  //   [0, 6.29MB): wb (GEMM weights)  -- after GEMM, reused as AB (4MB) + Cin (2MB)
  unsigned short* wb   = (unsigned short*)(ws);
  float4*         AB   = (float4*)(ws);
  float*          Cin  = (float*)(ws + 4194304);
  unsigned short* xtb  = (unsigned short*)(ws + 6291456);
  unsigned short* fbuf = (unsigned short*)(ws + 73400320);
  unsigned short* rbuf = (unsigned short*)(ws + 140509184);
  // xb (bf16 x, 64MB) lives in d_out's h region (dead until pass 3 rewrites it)
  unsigned short* xb = (unsigned short*)d_out;

  k_convert_x<<<2048, 256, 0, stream>>>((const float4*)x, (ushort4*)xb, MDIM * KDIM / 4);
  k_convert_w<<<(NDIM * KDIM) / 256, 256, 0, stream>>>(w, wb);

  k_gemm256<<<1536, 512, 0, stream>>>(xb, wb, bias, xtb, fbuf, rbuf);

  k_scan1<<<dim3(32, NSEG), 256, 0, stream>>>(fbuf, xtb, AB);
  k_scan2<<<32, 256, 0, stream>>>(c0, AB, Cin, out + (size_t)L_SEQ * CH);
  k_scan3<<<dim3(32, NSEG), 256, 0, stream>>>(x, fbuf, xtb, rbuf, Cin, out);
}